// Round 1
// baseline (473.019 us; speedup 1.0000x reference)
//
#include <hip/hip_runtime.h>
#include <hip/hip_bf16.h>

#define EMBED 1024
#define NHEAD 16
#define HDIM  64
#define BATCH 4
#define SEQ   2048
#define BT    (BATCH*SEQ)
#define NQKV  (3*EMBED)

using bf16x8 = __attribute__((ext_vector_type(8))) short;
using f32x4  = __attribute__((ext_vector_type(4))) float;

__device__ __forceinline__ unsigned short f2bf(float f){
  union { float f; unsigned u; } v; v.f = f;
  unsigned r = v.u + 0x7FFFu + ((v.u >> 16) & 1u);
  return (unsigned short)(r >> 16);
}

__device__ __forceinline__ void gload_lds16(const void* g, void* l){
  __builtin_amdgcn_global_load_lds(
      (const __attribute__((address_space(1))) void*)g,
      (__attribute__((address_space(3))) void*)l, 16, 0, 0);
}

// ---------------- fp32 -> bf16 elementwise convert ----------------
__global__ __launch_bounds__(256) void cvt_f32_bf16_k(
    const float* __restrict__ in, unsigned short* __restrict__ out, int n)
{
  int i = (blockIdx.x * 256 + threadIdx.x) * 4;
  if (i >= n) return;
  float4 v = *(const float4*)&in[i];
  ushort4 o;
  o.x = f2bf(v.x); o.y = f2bf(v.y); o.z = f2bf(v.z); o.w = f2bf(v.w);
  *(ushort4*)&out[i] = o;
}

// ------------- fp32 [R][C] -> bf16 transposed [C][R] -------------
__global__ __launch_bounds__(256) void transpose_cvt_k(
    const float* __restrict__ in, unsigned short* __restrict__ out, int R, int C)
{
  __shared__ float tile[32][33];
  int tx = threadIdx.x, ty = threadIdx.y;
  int c0 = blockIdx.x * 32, r0 = blockIdx.y * 32;
#pragma unroll
  for (int j = ty; j < 32; j += 8)
    tile[j][tx] = in[(size_t)(r0 + j) * C + c0 + tx];
  __syncthreads();
#pragma unroll
  for (int j = ty; j < 32; j += 8)
    out[(size_t)(c0 + j) * R + r0 + tx] = f2bf(tile[tx][j]);
}

// ---------------- bf16 GEMM, B^T layout (m97 structure) ----------------
// C[M][N] = A[M][K] * Bt[N][K]^T + bias[N]
// EPI==0: scatter into Q/K/V [BH][T][D] bf16.  EPI==1: fp32 out, row-major.
template<int EPI>
__global__ __launch_bounds__(256) void gemm_bt(
    const unsigned short* __restrict__ A,
    const unsigned short* __restrict__ Bt,
    const float* __restrict__ bias,
    unsigned short* __restrict__ qp,
    unsigned short* __restrict__ kp,
    unsigned short* __restrict__ vp,
    float* __restrict__ outp,
    int M, int N, int K)
{
  __shared__ unsigned short As[128 * 64];
  __shared__ unsigned short Bs[128 * 64];
  const int tid = threadIdx.x;
  const int w = tid >> 6, lane = tid & 63;
  const int lr = lane & 15, lg = lane >> 4;
  const int m0 = blockIdx.x * 128, n0 = blockIdx.y * 128;
  const int wm = (w >> 1) * 64, wn = (w & 1) * 64;
  const int fbase = w * 4;
  f32x4 acc[4][4] = {};

  for (int kt = 0; kt < K; kt += 64) {
    __syncthreads();
#pragma unroll
    for (int i = 0; i < 4; i++) {
      int f = (fbase + i) * 64 + lane;
      int row = f >> 3, col = (f & 7) * 8;
      gload_lds16(A  + (size_t)(m0 + row) * K + kt + col, &As[(fbase + i) * 512]);
      gload_lds16(Bt + (size_t)(n0 + row) * K + kt + col, &Bs[(fbase + i) * 512]);
    }
    __syncthreads();
#pragma unroll
    for (int kk = 0; kk < 2; kk++) {
      bf16x8 af[4], bv[4];
#pragma unroll
      for (int mi = 0; mi < 4; mi++)
        af[mi] = *(const bf16x8*)&As[(wm + mi * 16 + lr) * 64 + kk * 32 + lg * 8];
#pragma unroll
      for (int ni = 0; ni < 4; ni++)
        bv[ni] = *(const bf16x8*)&Bs[(wn + ni * 16 + lr) * 64 + kk * 32 + lg * 8];
#pragma unroll
      for (int mi = 0; mi < 4; mi++)
#pragma unroll
        for (int ni = 0; ni < 4; ni++)
          acc[mi][ni] = __builtin_amdgcn_mfma_f32_16x16x32_bf16(af[mi], bv[ni], acc[mi][ni], 0, 0, 0);
    }
  }

#pragma unroll
  for (int mi = 0; mi < 4; mi++)
#pragma unroll
    for (int ni = 0; ni < 4; ni++)
#pragma unroll
      for (int r = 0; r < 4; r++) {
        int row = m0 + wm + mi * 16 + lg * 4 + r;
        int col = n0 + wn + ni * 16 + lr;
        float val = acc[mi][ni][r] + bias[col];
        if (EPI == 0) {
          int s = col >> 10, hh = (col & 1023) >> 6, d = col & 63;
          int b = row >> 11, t = row & 2047;
          unsigned short* dst = (s == 0) ? qp : ((s == 1) ? kp : vp);
          dst[(((size_t)(b * NHEAD + hh) * SEQ) + t) * HDIM + d] = f2bf(val);
        } else {
          outp[(size_t)row * N + col] = val;
        }
      }
}

// ---------------- causal flash attention ----------------
// Q,K,V: [BH][T][D] bf16.  Y: [B*T][C] bf16 (head-interleaved cols).
__global__ __launch_bounds__(256) void attn_k(
    const unsigned short* __restrict__ Q,
    const unsigned short* __restrict__ K,
    const unsigned short* __restrict__ V,
    unsigned short* __restrict__ Y)
{
  __shared__ unsigned short Ks[64 * 64];
  __shared__ unsigned short Vt[64 * 72];      // [d][k], stride 72 (pad)
  __shared__ unsigned short Ps[4][16 * 64];   // per-wave P tile [16][64]

  const int tid = threadIdx.x;
  const int w = tid >> 6, lane = tid & 63;
  const int lr = lane & 15, lg = lane >> 4;
  const int qb = blockIdx.x, bh = blockIdx.y;
  const int b = bh >> 4, h = bh & 15;
  const size_t base = (size_t)bh * SEQ * HDIM;
  const int q0 = qb * 64;
  const float NEG = -1e30f;

  // Q fragments held in registers for the whole kernel
  bf16x8 aq[2];
  {
    int qrow = q0 + w * 16 + lr;
#pragma unroll
    for (int kk = 0; kk < 2; kk++)
      aq[kk] = *(const bf16x8*)&Q[base + (size_t)qrow * HDIM + kk * 32 + lg * 8];
  }

  f32x4 o[4] = {};
  float m[4], su[4];
#pragma unroll
  for (int r = 0; r < 4; r++) { m[r] = NEG; su[r] = 0.f; }

  for (int kb = 0; kb <= qb; kb++) {
    __syncthreads();
    // stage K tile [64][64] via global_load_lds
#pragma unroll
    for (int i = 0; i < 2; i++) {
      int f = (w * 2 + i) * 64 + lane;
      int row = f >> 3, col = (f & 7) * 8;
      gload_lds16(K + base + (size_t)(kb * 64 + row) * HDIM + col, &Ks[(w * 2 + i) * 512]);
    }
    // stage V transposed [d][k] via registers
#pragma unroll
    for (int i = 0; i < 2; i++) {
      int f = i * 256 + tid;
      int row = f >> 3, col = (f & 7) * 8;
      bf16x8 v8 = *(const bf16x8*)&V[base + (size_t)(kb * 64 + row) * HDIM + col];
#pragma unroll
      for (int e = 0; e < 8; e++)
        Vt[(col + e) * 72 + row] = ((unsigned short*)&v8)[e];
    }
    __syncthreads();

    // S = Q K^T
    f32x4 s[4] = {};
#pragma unroll
    for (int kk = 0; kk < 2; kk++) {
      bf16x8 bk[4];
#pragma unroll
      for (int n = 0; n < 4; n++)
        bk[n] = *(const bf16x8*)&Ks[(n * 16 + lr) * 64 + kk * 32 + lg * 8];
#pragma unroll
      for (int n = 0; n < 4; n++)
        s[n] = __builtin_amdgcn_mfma_f32_16x16x32_bf16(aq[kk], bk[n], s[n], 0, 0, 0);
    }

    // scale + causal mask (only diagonal block needs mask)
    float pm[4];
#pragma unroll
    for (int r = 0; r < 4; r++) pm[r] = NEG;
    const bool diag = (kb == qb);
#pragma unroll
    for (int n = 0; n < 4; n++)
#pragma unroll
      for (int r = 0; r < 4; r++) {
        float sv = s[n][r] * 0.125f;
        if (diag) {
          int cg = kb * 64 + n * 16 + lr;
          int rg = q0 + w * 16 + lg * 4 + r;
          if (cg > rg) sv = NEG;
        }
        s[n][r] = sv;
        pm[r] = fmaxf(pm[r], sv);
      }
    // row max across 16 lanes (cols)
#pragma unroll
    for (int mask = 1; mask < 16; mask <<= 1)
#pragma unroll
      for (int r = 0; r < 4; r++) pm[r] = fmaxf(pm[r], __shfl_xor(pm[r], mask, 64));

    float fac[4], rs[4];
#pragma unroll
    for (int r = 0; r < 4; r++) {
      float mn = fmaxf(m[r], pm[r]);
      fac[r] = __expf(m[r] - mn);
      m[r] = mn;
      rs[r] = 0.f;
    }
    // P = exp(S - m), write to per-wave LDS tile in A-layout source form
#pragma unroll
    for (int n = 0; n < 4; n++)
#pragma unroll
      for (int r = 0; r < 4; r++) {
        float p = __expf(s[n][r] - m[r]);
        rs[r] += p;
        Ps[w][(lg * 4 + r) * 64 + n * 16 + lr] = f2bf(p);
      }
#pragma unroll
    for (int mask = 1; mask < 16; mask <<= 1)
#pragma unroll
      for (int r = 0; r < 4; r++) rs[r] += __shfl_xor(rs[r], mask, 64);
#pragma unroll
    for (int r = 0; r < 4; r++) su[r] = su[r] * fac[r] + rs[r];
#pragma unroll
    for (int n = 0; n < 4; n++)
#pragma unroll
      for (int r = 0; r < 4; r++) o[n][r] *= fac[r];

    // O += P V
#pragma unroll
    for (int kc = 0; kc < 2; kc++) {
      bf16x8 ap = *(const bf16x8*)&Ps[w][lr * 64 + kc * 32 + lg * 8];
#pragma unroll
      for (int n = 0; n < 4; n++) {
        bf16x8 bv = *(const bf16x8*)&Vt[(n * 16 + lr) * 72 + kc * 32 + lg * 8];
        o[n] = __builtin_amdgcn_mfma_f32_16x16x32_bf16(ap, bv, o[n], 0, 0, 0);
      }
    }
  }

  // epilogue: normalize and write Y[b*T+t][h*64+d] bf16
#pragma unroll
  for (int n = 0; n < 4; n++)
#pragma unroll
    for (int r = 0; r < 4; r++) {
      int t = q0 + w * 16 + lg * 4 + r;
      int col = h * HDIM + n * 16 + lr;
      float val = o[n][r] / su[r];
      Y[((size_t)(b * SEQ + t)) * EMBED + col] = f2bf(val);
    }
}

// ---------------- host launch ----------------
extern "C" void kernel_launch(void* const* d_in, const int* in_sizes, int n_in,
                              void* d_out, int out_size, void* d_ws, size_t ws_size,
                              hipStream_t stream) {
  const float* x     = (const float*)d_in[0];
  const float* w_qkv = (const float*)d_in[1];
  const float* b_qkv = (const float*)d_in[2];
  const float* w_out = (const float*)d_in[3];
  const float* b_out = (const float*)d_in[4];
  float* outp = (float*)d_out;

  char* ws = (char*)d_ws;
  unsigned short* xb    = (unsigned short*)ws; ws += (size_t)BT * EMBED * 2;
  unsigned short* wqkvT = (unsigned short*)ws; ws += (size_t)NQKV * EMBED * 2;
  unsigned short* woutT = (unsigned short*)ws; ws += (size_t)EMBED * EMBED * 2;
  unsigned short* Qb    = (unsigned short*)ws; ws += (size_t)BATCH * NHEAD * SEQ * HDIM * 2;
  unsigned short* Kb    = (unsigned short*)ws; ws += (size_t)BATCH * NHEAD * SEQ * HDIM * 2;
  unsigned short* Vb    = (unsigned short*)ws; ws += (size_t)BATCH * NHEAD * SEQ * HDIM * 2;
  unsigned short* Yb    = (unsigned short*)ws; ws += (size_t)BT * EMBED * 2;

  // converts
  cvt_f32_bf16_k<<<(BT * EMBED) / 1024, 256, 0, stream>>>(x, xb, BT * EMBED);
  transpose_cvt_k<<<dim3(NQKV / 32, EMBED / 32), dim3(32, 8), 0, stream>>>(w_qkv, wqkvT, EMBED, NQKV);
  transpose_cvt_k<<<dim3(EMBED / 32, EMBED / 32), dim3(32, 8), 0, stream>>>(w_out, woutT, EMBED, EMBED);

  // QKV projection, scatter to Q/K/V
  gemm_bt<0><<<dim3(BT / 128, NQKV / 128), 256, 0, stream>>>(
      xb, wqkvT, b_qkv, Qb, Kb, Vb, nullptr, BT, NQKV, EMBED);

  // causal attention
  attn_k<<<dim3(SEQ / 64, BATCH * NHEAD), 256, 0, stream>>>(Qb, Kb, Vb, Yb);

  // output projection
  gemm_bt<1><<<dim3(BT / 128, EMBED / 128), 256, 0, stream>>>(
      Yb, woutT, b_out, nullptr, nullptr, nullptr, outp, BT, EMBED, EMBED);
}

// Round 2
// 274.746 us; speedup vs baseline: 1.7217x; 1.7217x over previous
//
#include <hip/hip_runtime.h>
#include <hip/hip_bf16.h>

#define EMBED 1024
#define NHEAD 16
#define HDIM  64
#define BATCH 4
#define SEQ   2048
#define BT    (BATCH*SEQ)
#define NQKV  (3*EMBED)

using bf16x8 = __attribute__((ext_vector_type(8))) short;
using f32x4  = __attribute__((ext_vector_type(4))) float;

__device__ __forceinline__ unsigned short f2bf(float f){
  union { float f; unsigned u; } v; v.f = f;
  unsigned r = v.u + 0x7FFFu + ((v.u >> 16) & 1u);
  return (unsigned short)(r >> 16);
}

__device__ __forceinline__ void gload_lds16(const void* g, void* l){
  __builtin_amdgcn_global_load_lds(
      (const __attribute__((address_space(1))) void*)g,
      (__attribute__((address_space(3))) void*)l, 16, 0, 0);
}

// ---------------- fp32 -> bf16 elementwise convert ----------------
__global__ __launch_bounds__(256) void cvt_f32_bf16_k(
    const float* __restrict__ in, unsigned short* __restrict__ out, int n)
{
  int i = (blockIdx.x * 256 + threadIdx.x) * 4;
  if (i >= n) return;
  float4 v = *(const float4*)&in[i];
  ushort4 o;
  o.x = f2bf(v.x); o.y = f2bf(v.y); o.z = f2bf(v.z); o.w = f2bf(v.w);
  *(ushort4*)&out[i] = o;
}

// ------------- fp32 [R][C] -> bf16 transposed [C][R] -------------
__global__ __launch_bounds__(256) void transpose_cvt_k(
    const float* __restrict__ in, unsigned short* __restrict__ out, int R, int C)
{
  __shared__ float tile[32][33];
  int tx = threadIdx.x, ty = threadIdx.y;
  int c0 = blockIdx.x * 32, r0 = blockIdx.y * 32;
#pragma unroll
  for (int j = ty; j < 32; j += 8)
    tile[j][tx] = in[(size_t)(r0 + j) * C + c0 + tx];
  __syncthreads();
#pragma unroll
  for (int j = ty; j < 32; j += 8)
    out[(size_t)(c0 + j) * R + r0 + tx] = f2bf(tile[tx][j]);
}

// ---------------- bf16 GEMM, B^T layout (m97 structure) ----------------
// C[M][N] = A[M][K] * Bt[N][K]^T + bias[N]
// EPI==0: scatter into Q/K [BH][T][D] bf16, V^T [BH][D][T] bf16.
// EPI==1: fp32 out, row-major.
template<int EPI>
__global__ __launch_bounds__(256) void gemm_bt(
    const unsigned short* __restrict__ A,
    const unsigned short* __restrict__ Bt,
    const float* __restrict__ bias,
    unsigned short* __restrict__ qp,
    unsigned short* __restrict__ kp,
    unsigned short* __restrict__ vp,
    float* __restrict__ outp,
    int M, int N, int K)
{
  __shared__ unsigned short As[128 * 64];
  __shared__ unsigned short Bs[128 * 64];
  const int tid = threadIdx.x;
  const int w = tid >> 6, lane = tid & 63;
  const int lr = lane & 15, lg = lane >> 4;
  const int m0 = blockIdx.x * 128, n0 = blockIdx.y * 128;
  const int wm = (w >> 1) * 64, wn = (w & 1) * 64;
  const int fbase = w * 4;
  f32x4 acc[4][4] = {};

  for (int kt = 0; kt < K; kt += 64) {
    __syncthreads();
#pragma unroll
    for (int i = 0; i < 4; i++) {
      int f = (fbase + i) * 64 + lane;
      int row = f >> 3, col = (f & 7) * 8;
      gload_lds16(A  + (size_t)(m0 + row) * K + kt + col, &As[(fbase + i) * 512]);
      gload_lds16(Bt + (size_t)(n0 + row) * K + kt + col, &Bs[(fbase + i) * 512]);
    }
    __syncthreads();
#pragma unroll
    for (int kk = 0; kk < 2; kk++) {
      bf16x8 af[4], bv[4];
#pragma unroll
      for (int mi = 0; mi < 4; mi++)
        af[mi] = *(const bf16x8*)&As[(wm + mi * 16 + lr) * 64 + kk * 32 + lg * 8];
#pragma unroll
      for (int ni = 0; ni < 4; ni++)
        bv[ni] = *(const bf16x8*)&Bs[(wn + ni * 16 + lr) * 64 + kk * 32 + lg * 8];
#pragma unroll
      for (int mi = 0; mi < 4; mi++)
#pragma unroll
        for (int ni = 0; ni < 4; ni++)
          acc[mi][ni] = __builtin_amdgcn_mfma_f32_16x16x32_bf16(af[mi], bv[ni], acc[mi][ni], 0, 0, 0);
    }
  }

#pragma unroll
  for (int mi = 0; mi < 4; mi++)
#pragma unroll
    for (int ni = 0; ni < 4; ni++) {
      const int rowb = m0 + wm + mi * 16 + lg * 4;
      const int colb = n0 + wn + ni * 16 + lr;
      const float bv_ = bias[colb];
      if (EPI == 0) {
        int s = colb >> 10, hh = (colb & 1023) >> 6, d = colb & 63;
        int b = rowb >> 11, t = rowb & 2047;
        if (s == 2) {
          // V^T layout [BH][D][T]; t contiguous over r -> ushort4 store
          ushort4 o4;
          o4.x = f2bf(acc[mi][ni][0] + bv_);
          o4.y = f2bf(acc[mi][ni][1] + bv_);
          o4.z = f2bf(acc[mi][ni][2] + bv_);
          o4.w = f2bf(acc[mi][ni][3] + bv_);
          *(ushort4*)&vp[((size_t)(b * NHEAD + hh) * HDIM + d) * SEQ + t] = o4;
        } else {
          unsigned short* dst = (s == 0) ? qp : kp;
#pragma unroll
          for (int r = 0; r < 4; r++)
            dst[((size_t)(b * NHEAD + hh) * SEQ + t + r) * HDIM + d] =
                f2bf(acc[mi][ni][r] + bv_);
        }
      } else {
#pragma unroll
        for (int r = 0; r < 4; r++)
          outp[(size_t)(rowb + r) * N + colb] = acc[mi][ni][r] + bv_;
      }
    }
}

// ---------------- causal flash attention ----------------
// Q,K: [BH][T][D] bf16.  Vt: [BH][D][T] bf16.  Y: [B*T][C] bf16.
// Grid (16, 64): block bx handles qb = 31-bx then qb = bx (33 tiles each).
// LDS tiles XOR-swizzled (T2): element E stored at E ^ ((row&7)<<3).
__global__ __launch_bounds__(256) void attn_k(
    const unsigned short* __restrict__ Q,
    const unsigned short* __restrict__ K,
    const unsigned short* __restrict__ Vt,
    unsigned short* __restrict__ Y)
{
  __shared__ unsigned short Ks[2][64 * 64];
  __shared__ unsigned short Vs[2][64 * 64];
  __shared__ unsigned short Ps[4][16 * 64];

  const int tid = threadIdx.x;
  const int w = tid >> 6, lane = tid & 63;
  const int lr = lane & 15, lg = lane >> 4;
  const int bh = blockIdx.y;
  const int b = bh >> 4, h = bh & 15;
  const size_t base = (size_t)bh * SEQ * HDIM;   // Q,K and Vt (same extent)
  const float NEG = -1e30f;
  const float SCL = 0.125f * 1.44269504f;        // 1/sqrt(D) * log2(e)

  for (int seg = 0; seg < 2; seg++) {
    const int qb = seg ? (int)blockIdx.x : (31 - (int)blockIdx.x);
    const int q0 = qb * 64;
    const int nk = qb + 1;

    // Q fragments in registers
    bf16x8 aq[2];
    {
      int qrow = q0 + w * 16 + lr;
#pragma unroll
      for (int kk = 0; kk < 2; kk++)
        aq[kk] = *(const bf16x8*)&Q[base + (size_t)qrow * HDIM + kk * 32 + lg * 8];
    }

    f32x4 o[4] = {};
    float m[4], su[4];
#pragma unroll
    for (int r = 0; r < 4; r++) { m[r] = NEG; su[r] = 0.f; }

    // ---- stage tile 0 into buf 0 (pre-swizzled source chunks) ----
#pragma unroll
    for (int i = 0; i < 2; i++) {
      int f = (w * 2 + i) * 64 + lane;
      int row = f >> 3, sc = (f & 7) ^ (row & 7);
      gload_lds16(K  + base + (size_t)row * HDIM + sc * 8, &Ks[0][f * 8]);
      gload_lds16(Vt + base + (size_t)row * SEQ  + sc * 8, &Vs[0][f * 8]);
    }
    __syncthreads();

    int cur = 0;
    for (int kb = 0; kb < nk; kb++) {
      // issue next tile's staging (overlaps with compute below)
      if (kb + 1 < nk) {
        const int nb = kb + 1;
#pragma unroll
        for (int i = 0; i < 2; i++) {
          int f = (w * 2 + i) * 64 + lane;
          int row = f >> 3, sc = (f & 7) ^ (row & 7);
          gload_lds16(K  + base + (size_t)(nb * 64 + row) * HDIM + sc * 8,
                      &Ks[cur ^ 1][f * 8]);
          gload_lds16(Vt + base + (size_t)row * SEQ + nb * 64 + sc * 8,
                      &Vs[cur ^ 1][f * 8]);
        }
      }

      // ---- S = Q K^T (swizzled reads) ----
      f32x4 s[4] = {};
#pragma unroll
      for (int kk = 0; kk < 2; kk++) {
        bf16x8 bk[4];
#pragma unroll
        for (int n = 0; n < 4; n++) {
          int E = (n * 16 + lr) * 64 + kk * 32 + lg * 8;
          bk[n] = *(const bf16x8*)&Ks[cur][E ^ ((lr & 7) << 3)];
        }
#pragma unroll
        for (int n = 0; n < 4; n++)
          s[n] = __builtin_amdgcn_mfma_f32_16x16x32_bf16(aq[kk], bk[n], s[n], 0, 0, 0);
      }

      // ---- scale (base-2) + causal mask + row max ----
      float pm[4];
#pragma unroll
      for (int r = 0; r < 4; r++) pm[r] = NEG;
      const bool diag = (kb == qb);
#pragma unroll
      for (int n = 0; n < 4; n++)
#pragma unroll
        for (int r = 0; r < 4; r++) {
          float sv = s[n][r] * SCL;
          if (diag) {
            int cg = kb * 64 + n * 16 + lr;
            int rg = q0 + w * 16 + lg * 4 + r;
            if (cg > rg) sv = NEG;
          }
          s[n][r] = sv;
          pm[r] = fmaxf(pm[r], sv);
        }
#pragma unroll
      for (int mask = 1; mask < 16; mask <<= 1)
#pragma unroll
        for (int r = 0; r < 4; r++) pm[r] = fmaxf(pm[r], __shfl_xor(pm[r], mask, 64));

      float fac[4], rs[4];
#pragma unroll
      for (int r = 0; r < 4; r++) {
        float mn = fmaxf(m[r], pm[r]);
        fac[r] = exp2f(m[r] - mn);
        m[r] = mn;
        rs[r] = 0.f;
      }
      // P = 2^(s - m), write to per-wave swizzled LDS tile
#pragma unroll
      for (int n = 0; n < 4; n++)
#pragma unroll
        for (int r = 0; r < 4; r++) {
          float p = exp2f(s[n][r] - m[r]);
          rs[r] += p;
          int prow = lg * 4 + r;
          int E = prow * 64 + n * 16 + lr;
          Ps[w][E ^ ((prow & 7) << 3)] = f2bf(p);
        }
#pragma unroll
      for (int mask = 1; mask < 16; mask <<= 1)
#pragma unroll
        for (int r = 0; r < 4; r++) rs[r] += __shfl_xor(rs[r], mask, 64);
#pragma unroll
      for (int r = 0; r < 4; r++) su[r] = su[r] * fac[r] + rs[r];
#pragma unroll
      for (int n = 0; n < 4; n++)
#pragma unroll
        for (int r = 0; r < 4; r++) o[n][r] *= fac[r];

      // ---- O += P V (swizzled reads) ----
#pragma unroll
      for (int kc = 0; kc < 2; kc++) {
        int Ea = lr * 64 + kc * 32 + lg * 8;
        bf16x8 ap = *(const bf16x8*)&Ps[w][Ea ^ ((lr & 7) << 3)];
#pragma unroll
        for (int n = 0; n < 4; n++) {
          int E = (n * 16 + lr) * 64 + kc * 32 + lg * 8;
          bf16x8 bv = *(const bf16x8*)&Vs[cur][E ^ ((lr & 7) << 3)];
          o[n] = __builtin_amdgcn_mfma_f32_16x16x32_bf16(ap, bv, o[n], 0, 0, 0);
        }
      }

      __syncthreads();   // drains staging vmcnt + tile reuse barrier
      cur ^= 1;
    }

    // epilogue: normalize and write Y[b*T+t][h*64+d] bf16
#pragma unroll
    for (int n = 0; n < 4; n++)
#pragma unroll
      for (int r = 0; r < 4; r++) {
        int t = q0 + w * 16 + lg * 4 + r;
        int col = h * HDIM + n * 16 + lr;
        float val = o[n][r] / su[r];
        Y[((size_t)(b * SEQ + t)) * EMBED + col] = f2bf(val);
      }
  }
}

// ---------------- host launch ----------------
extern "C" void kernel_launch(void* const* d_in, const int* in_sizes, int n_in,
                              void* d_out, int out_size, void* d_ws, size_t ws_size,
                              hipStream_t stream) {
  const float* x     = (const float*)d_in[0];
  const float* w_qkv = (const float*)d_in[1];
  const float* b_qkv = (const float*)d_in[2];
  const float* w_out = (const float*)d_in[3];
  const float* b_out = (const float*)d_in[4];
  float* outp = (float*)d_out;

  char* ws = (char*)d_ws;
  unsigned short* xb    = (unsigned short*)ws; ws += (size_t)BT * EMBED * 2;
  unsigned short* wqkvT = (unsigned short*)ws; ws += (size_t)NQKV * EMBED * 2;
  unsigned short* woutT = (unsigned short*)ws; ws += (size_t)EMBED * EMBED * 2;
  unsigned short* Qb    = (unsigned short*)ws; ws += (size_t)BATCH * NHEAD * SEQ * HDIM * 2;
  unsigned short* Kb    = (unsigned short*)ws; ws += (size_t)BATCH * NHEAD * SEQ * HDIM * 2;
  unsigned short* Vb    = (unsigned short*)ws; ws += (size_t)BATCH * NHEAD * SEQ * HDIM * 2;
  unsigned short* Yb    = (unsigned short*)ws; ws += (size_t)BT * EMBED * 2;

  // converts
  cvt_f32_bf16_k<<<(BT * EMBED) / 1024, 256, 0, stream>>>(x, xb, BT * EMBED);
  transpose_cvt_k<<<dim3(NQKV / 32, EMBED / 32), dim3(32, 8), 0, stream>>>(w_qkv, wqkvT, EMBED, NQKV);
  transpose_cvt_k<<<dim3(EMBED / 32, EMBED / 32), dim3(32, 8), 0, stream>>>(w_out, woutT, EMBED, EMBED);

  // QKV projection, scatter to Q/K/V^T
  gemm_bt<0><<<dim3(BT / 128, NQKV / 128), 256, 0, stream>>>(
      xb, wqkvT, b_qkv, Qb, Kb, Vb, nullptr, BT, NQKV, EMBED);

  // causal attention (balanced persistent pairing)
  attn_k<<<dim3(SEQ / 128, BATCH * NHEAD), 256, 0, stream>>>(Qb, Kb, Vb, Yb);

  // output projection
  gemm_bt<1><<<dim3(BT / 128, EMBED / 128), 256, 0, stream>>>(
      Yb, woutT, b_out, nullptr, nullptr, nullptr, outp, BT, EMBED, EMBED);
}

// Round 3
// 238.070 us; speedup vs baseline: 1.9869x; 1.1541x over previous
//
#include <hip/hip_runtime.h>
#include <hip/hip_bf16.h>

#define EMBED 1024
#define NHEAD 16
#define HDIM  64
#define BATCH 4
#define SEQ   2048
#define BT    (BATCH*SEQ)
#define NQKV  (3*EMBED)

using bf16x8 = __attribute__((ext_vector_type(8))) short;
using f32x4  = __attribute__((ext_vector_type(4))) float;

__device__ __forceinline__ unsigned short f2bf(float f){
  union { float f; unsigned u; } v; v.f = f;
  unsigned r = v.u + 0x7FFFu + ((v.u >> 16) & 1u);
  return (unsigned short)(r >> 16);
}

__device__ __forceinline__ unsigned pack_bf2(float a, float b){
  float2 t; t.x = a; t.y = b;
  __hip_bfloat162 h = __float22bfloat162_rn(t);
  union { __hip_bfloat162 h; unsigned u; } c; c.h = h;
  return c.u;
}

__device__ __forceinline__ void gload_lds16(const void* g, void* l){
  __builtin_amdgcn_global_load_lds(
      (const __attribute__((address_space(1))) void*)g,
      (__attribute__((address_space(3))) void*)l, 16, 0, 0);
}

// ---------------- fp32 -> bf16 elementwise convert ----------------
__global__ __launch_bounds__(256) void cvt_f32_bf16_k(
    const float* __restrict__ in, unsigned short* __restrict__ out, int n)
{
  int i = (blockIdx.x * 256 + threadIdx.x) * 4;
  if (i >= n) return;
  float4 v = *(const float4*)&in[i];
  ushort4 o;
  o.x = f2bf(v.x); o.y = f2bf(v.y); o.z = f2bf(v.z); o.w = f2bf(v.w);
  *(ushort4*)&out[i] = o;
}

// ------------- fp32 [R][C] -> bf16 transposed [C][R] -------------
__global__ __launch_bounds__(256) void transpose_cvt_k(
    const float* __restrict__ in, unsigned short* __restrict__ out, int R, int C)
{
  __shared__ float tile[32][33];
  int tx = threadIdx.x, ty = threadIdx.y;
  int c0 = blockIdx.x * 32, r0 = blockIdx.y * 32;
#pragma unroll
  for (int j = ty; j < 32; j += 8)
    tile[j][tx] = in[(size_t)(r0 + j) * C + c0 + tx];
  __syncthreads();
#pragma unroll
  for (int j = ty; j < 32; j += 8)
    out[(size_t)(c0 + j) * R + r0 + tx] = f2bf(tile[tx][j]);
}

// ---------------- bf16 GEMM, B^T layout (m97 structure) ----------------
template<int EPI>
__global__ __launch_bounds__(256) void gemm_bt(
    const unsigned short* __restrict__ A,
    const unsigned short* __restrict__ Bt,
    const float* __restrict__ bias,
    unsigned short* __restrict__ qp,
    unsigned short* __restrict__ kp,
    unsigned short* __restrict__ vp,
    float* __restrict__ outp,
    int M, int N, int K)
{
  __shared__ unsigned short As[128 * 64];
  __shared__ unsigned short Bs[128 * 64];
  const int tid = threadIdx.x;
  const int w = tid >> 6, lane = tid & 63;
  const int lr = lane & 15, lg = lane >> 4;
  const int m0 = blockIdx.x * 128, n0 = blockIdx.y * 128;
  const int wm = (w >> 1) * 64, wn = (w & 1) * 64;
  const int fbase = w * 4;
  f32x4 acc[4][4] = {};

  for (int kt = 0; kt < K; kt += 64) {
    __syncthreads();
#pragma unroll
    for (int i = 0; i < 4; i++) {
      int f = (fbase + i) * 64 + lane;
      int row = f >> 3, col = (f & 7) * 8;
      gload_lds16(A  + (size_t)(m0 + row) * K + kt + col, &As[(fbase + i) * 512]);
      gload_lds16(Bt + (size_t)(n0 + row) * K + kt + col, &Bs[(fbase + i) * 512]);
    }
    __syncthreads();
#pragma unroll
    for (int kk = 0; kk < 2; kk++) {
      bf16x8 af[4], bv[4];
#pragma unroll
      for (int mi = 0; mi < 4; mi++)
        af[mi] = *(const bf16x8*)&As[(wm + mi * 16 + lr) * 64 + kk * 32 + lg * 8];
#pragma unroll
      for (int ni = 0; ni < 4; ni++)
        bv[ni] = *(const bf16x8*)&Bs[(wn + ni * 16 + lr) * 64 + kk * 32 + lg * 8];
#pragma unroll
      for (int mi = 0; mi < 4; mi++)
#pragma unroll
        for (int ni = 0; ni < 4; ni++)
          acc[mi][ni] = __builtin_amdgcn_mfma_f32_16x16x32_bf16(af[mi], bv[ni], acc[mi][ni], 0, 0, 0);
    }
  }

#pragma unroll
  for (int mi = 0; mi < 4; mi++)
#pragma unroll
    for (int ni = 0; ni < 4; ni++) {
      const int rowb = m0 + wm + mi * 16 + lg * 4;
      const int colb = n0 + wn + ni * 16 + lr;
      const float bv_ = bias[colb];
      if (EPI == 0) {
        int s = colb >> 10, hh = (colb & 1023) >> 6, d = colb & 63;
        int b = rowb >> 11, t = rowb & 2047;
        if (s == 2) {
          ushort4 o4;
          o4.x = f2bf(acc[mi][ni][0] + bv_);
          o4.y = f2bf(acc[mi][ni][1] + bv_);
          o4.z = f2bf(acc[mi][ni][2] + bv_);
          o4.w = f2bf(acc[mi][ni][3] + bv_);
          *(ushort4*)&vp[((size_t)(b * NHEAD + hh) * HDIM + d) * SEQ + t] = o4;
        } else {
          unsigned short* dst = (s == 0) ? qp : kp;
#pragma unroll
          for (int r = 0; r < 4; r++)
            dst[((size_t)(b * NHEAD + hh) * SEQ + t + r) * HDIM + d] =
                f2bf(acc[mi][ni][r] + bv_);
        }
      } else {
#pragma unroll
        for (int r = 0; r < 4; r++)
          outp[(size_t)(rowb + r) * N + colb] = acc[mi][ni][r] + bv_;
      }
    }
}

// ---------------- causal flash attention (swapped QK^T softmax) ----------------
// Q,K: [BH][T][D] bf16.  Vt: [BH][D][T] bf16.  Y: [B*T][C] bf16.
// Grid (16, 64): block bx handles qb = 31-bx then qb = bx (33 tiles each).
// Ks/Vs XOR-swizzled elem^((row&7)<<3); Ps XOR-swizzled the same way.
__global__ __launch_bounds__(256) void attn_k(
    const unsigned short* __restrict__ Q,
    const unsigned short* __restrict__ K,
    const unsigned short* __restrict__ Vt,
    unsigned short* __restrict__ Y)
{
  __shared__ unsigned short Ks[2][64 * 64];
  __shared__ unsigned short Vs[2][64 * 64];
  __shared__ unsigned short Ps[4][16 * 64];

  const int tid = threadIdx.x;
  const int w = tid >> 6, lane = tid & 63;
  const int lr = lane & 15, lg = lane >> 4;
  const int bh = blockIdx.y;
  const int b = bh >> 4, h = bh & 15;
  const size_t base = (size_t)bh * SEQ * HDIM;
  const float NEG = -1e30f;
  const float SCL = 0.125f * 1.44269504f;   // 1/sqrt(D) * log2(e)
  const int pswz = (lr & 7) << 3;           // Ps element-index XOR

  for (int seg = 0; seg < 2; seg++) {
    const int qb = seg ? (int)blockIdx.x : (31 - (int)blockIdx.x);
    const int q0 = qb * 64;
    const int nk = qb + 1;

    // Q fragments in registers (q-row = lr; used as MFMA B-operand)
    bf16x8 aq[2];
    {
      int qrow = q0 + w * 16 + lr;
#pragma unroll
      for (int kk = 0; kk < 2; kk++)
        aq[kk] = *(const bf16x8*)&Q[base + (size_t)qrow * HDIM + kk * 32 + lg * 8];
    }

    f32x4 o[4] = {};
    float m = NEG, su = 0.f;

    // stage tile 0 into buf 0 (pre-swizzled source chunks)
#pragma unroll
    for (int i = 0; i < 2; i++) {
      int f = (w * 2 + i) * 64 + lane;
      int row = f >> 3, sc = (f & 7) ^ (row & 7);
      gload_lds16(K  + base + (size_t)row * HDIM + sc * 8, &Ks[0][f * 8]);
      gload_lds16(Vt + base + (size_t)row * SEQ  + sc * 8, &Vs[0][f * 8]);
    }
    __syncthreads();

    int cur = 0;
    for (int kb = 0; kb < nk; kb++) {
      if (kb + 1 < nk) {
        const int nb = kb + 1;
#pragma unroll
        for (int i = 0; i < 2; i++) {
          int f = (w * 2 + i) * 64 + lane;
          int row = f >> 3, sc = (f & 7) ^ (row & 7);
          gload_lds16(K  + base + (size_t)(nb * 64 + row) * HDIM + sc * 8,
                      &Ks[cur ^ 1][f * 8]);
          gload_lds16(Vt + base + (size_t)row * SEQ + nb * 64 + sc * 8,
                      &Vs[cur ^ 1][f * 8]);
        }
      }

      // ---- S^T = K Q^T : lane owns q = lr, k = kb*64 + n*16 + lg*4 + r ----
      f32x4 s[4] = {};
      __builtin_amdgcn_s_setprio(1);
#pragma unroll
      for (int kk = 0; kk < 2; kk++) {
        bf16x8 bk[4];
#pragma unroll
        for (int n = 0; n < 4; n++) {
          int E = (n * 16 + lr) * 64 + kk * 32 + lg * 8;
          bk[n] = *(const bf16x8*)&Ks[cur][E ^ ((lr & 7) << 3)];
        }
#pragma unroll
        for (int n = 0; n < 4; n++)
          s[n] = __builtin_amdgcn_mfma_f32_16x16x32_bf16(bk[n], aq[kk], s[n], 0, 0, 0);
      }
      __builtin_amdgcn_s_setprio(0);

      // ---- scale (base-2) + causal mask + per-lane row max ----
      const bool diag = (kb == qb);
      const int rg = q0 + w * 16 + lr;
      float pm = NEG;
#pragma unroll
      for (int n = 0; n < 4; n++)
#pragma unroll
        for (int r = 0; r < 4; r++) {
          float sv = s[n][r] * SCL;
          if (diag) {
            int cg = kb * 64 + n * 16 + lg * 4 + r;
            if (cg > rg) sv = NEG;
          }
          s[n][r] = sv;
          pm = fmaxf(pm, sv);
        }
      // reduce across the 4 lanes sharing this q (lg groups)
      pm = fmaxf(pm, __shfl_xor(pm, 16, 64));
      pm = fmaxf(pm, __shfl_xor(pm, 32, 64));

      // ---- defer-max (T13): only rescale when max grew past THR=8 ----
      const bool upd = __any(pm > m + 8.f);
      float fac = 1.f;
      if (upd) {
        float mn = fmaxf(m, pm);
        fac = exp2f(m - mn);
        m = mn;
      }

      // ---- P = 2^(s-m); pack k-consecutive quads; b64 write ----
      float rs = 0.f;
#pragma unroll
      for (int n = 0; n < 4; n++) {
        float p0 = exp2f(s[n][0] - m);
        float p1 = exp2f(s[n][1] - m);
        float p2 = exp2f(s[n][2] - m);
        float p3 = exp2f(s[n][3] - m);
        rs += (p0 + p1) + (p2 + p3);
        uint2 pk;
        pk.x = pack_bf2(p0, p1);
        pk.y = pack_bf2(p2, p3);
        int E = (lr * 64 + n * 16 + lg * 4) ^ pswz;
        *(uint2*)&Ps[w][E] = pk;
      }
      rs += __shfl_xor(rs, 16, 64);
      rs += __shfl_xor(rs, 32, 64);
      su = su * fac + rs;

      if (upd) {
        float facr[4];
#pragma unroll
        for (int r = 0; r < 4; r++) facr[r] = __shfl(fac, lg * 4 + r, 64);
#pragma unroll
        for (int n = 0; n < 4; n++)
#pragma unroll
          for (int r = 0; r < 4; r++) o[n][r] *= facr[r];
      }

      // ---- O += P V ----
      __builtin_amdgcn_s_setprio(1);
#pragma unroll
      for (int kc = 0; kc < 2; kc++) {
        int Ea = (lr * 64 + kc * 32 + lg * 8) ^ pswz;
        bf16x8 ap = *(const bf16x8*)&Ps[w][Ea];
#pragma unroll
        for (int n = 0; n < 4; n++) {
          int E = (n * 16 + lr) * 64 + kc * 32 + lg * 8;
          bf16x8 bv = *(const bf16x8*)&Vs[cur][E ^ ((lr & 7) << 3)];
          o[n] = __builtin_amdgcn_mfma_f32_16x16x32_bf16(ap, bv, o[n], 0, 0, 0);
        }
      }
      __builtin_amdgcn_s_setprio(0);

      __syncthreads();
      cur ^= 1;
    }

    // epilogue: normalize (su broadcast from q-owner lanes) and write Y
    float sur[4];
#pragma unroll
    for (int r = 0; r < 4; r++) sur[r] = __shfl(su, lg * 4 + r, 64);
#pragma unroll
    for (int n = 0; n < 4; n++)
#pragma unroll
      for (int r = 0; r < 4; r++) {
        int t = q0 + w * 16 + lg * 4 + r;
        int col = h * HDIM + n * 16 + lr;
        float val = o[n][r] / sur[r];
        Y[((size_t)(b * SEQ + t)) * EMBED + col] = f2bf(val);
      }
  }
}

// ---------------- host launch ----------------
extern "C" void kernel_launch(void* const* d_in, const int* in_sizes, int n_in,
                              void* d_out, int out_size, void* d_ws, size_t ws_size,
                              hipStream_t stream) {
  const float* x     = (const float*)d_in[0];
  const float* w_qkv = (const float*)d_in[1];
  const float* b_qkv = (const float*)d_in[2];
  const float* w_out = (const float*)d_in[3];
  const float* b_out = (const float*)d_in[4];
  float* outp = (float*)d_out;

  char* ws = (char*)d_ws;
  unsigned short* xb    = (unsigned short*)ws; ws += (size_t)BT * EMBED * 2;
  unsigned short* wqkvT = (unsigned short*)ws; ws += (size_t)NQKV * EMBED * 2;
  unsigned short* woutT = (unsigned short*)ws; ws += (size_t)EMBED * EMBED * 2;
  unsigned short* Qb    = (unsigned short*)ws; ws += (size_t)BATCH * NHEAD * SEQ * HDIM * 2;
  unsigned short* Kb    = (unsigned short*)ws; ws += (size_t)BATCH * NHEAD * SEQ * HDIM * 2;
  unsigned short* Vb    = (unsigned short*)ws; ws += (size_t)BATCH * NHEAD * SEQ * HDIM * 2;
  unsigned short* Yb    = (unsigned short*)ws; ws += (size_t)BT * EMBED * 2;

  cvt_f32_bf16_k<<<(BT * EMBED) / 1024, 256, 0, stream>>>(x, xb, BT * EMBED);
  transpose_cvt_k<<<dim3(NQKV / 32, EMBED / 32), dim3(32, 8), 0, stream>>>(w_qkv, wqkvT, EMBED, NQKV);
  transpose_cvt_k<<<dim3(EMBED / 32, EMBED / 32), dim3(32, 8), 0, stream>>>(w_out, woutT, EMBED, EMBED);

  gemm_bt<0><<<dim3(BT / 128, NQKV / 128), 256, 0, stream>>>(
      xb, wqkvT, b_qkv, Qb, Kb, Vb, nullptr, BT, NQKV, EMBED);

  attn_k<<<dim3(SEQ / 128, BATCH * NHEAD), 256, 0, stream>>>(Qb, Kb, Vb, Yb);

  gemm_bt<1><<<dim3(BT / 128, EMBED / 128), 256, 0, stream>>>(
      Yb, woutT, b_out, nullptr, nullptr, nullptr, outp, BT, EMBED, EMBED);
}

// Round 4
// 226.689 us; speedup vs baseline: 2.0866x; 1.0502x over previous
//
#include <hip/hip_runtime.h>
#include <hip/hip_bf16.h>

#define EMBED 1024
#define NHEAD 16
#define HDIM  64
#define BATCH 4
#define SEQ   2048
#define BT    (BATCH*SEQ)
#define NQKV  (3*EMBED)

using bf16x8 = __attribute__((ext_vector_type(8))) short;
using f32x4  = __attribute__((ext_vector_type(4))) float;

__device__ __forceinline__ unsigned short f2bf(float f){
  union { float f; unsigned u; } v; v.f = f;
  unsigned r = v.u + 0x7FFFu + ((v.u >> 16) & 1u);
  return (unsigned short)(r >> 16);
}

__device__ __forceinline__ unsigned pack_bf2(float a, float b){
  float2 t; t.x = a; t.y = b;
  __hip_bfloat162 h = __float22bfloat162_rn(t);
  union { __hip_bfloat162 h; unsigned u; } c; c.h = h;
  return c.u;
}

__device__ __forceinline__ void gload_lds16(const void* g, void* l){
  __builtin_amdgcn_global_load_lds(
      (const __attribute__((address_space(1))) void*)g,
      (__attribute__((address_space(3))) void*)l, 16, 0, 0);
}

// ---------------- fp32 -> bf16 elementwise convert ----------------
__global__ __launch_bounds__(256) void cvt_f32_bf16_k(
    const float* __restrict__ in, unsigned short* __restrict__ out, int n)
{
  int i = (blockIdx.x * 256 + threadIdx.x) * 4;
  if (i >= n) return;
  float4 v = *(const float4*)&in[i];
  ushort4 o;
  o.x = f2bf(v.x); o.y = f2bf(v.y); o.z = f2bf(v.z); o.w = f2bf(v.w);
  *(ushort4*)&out[i] = o;
}

// ------------- fp32 [R][C] -> bf16 transposed [C][R] -------------
__global__ __launch_bounds__(256) void transpose_cvt_k(
    const float* __restrict__ in, unsigned short* __restrict__ out, int R, int C)
{
  __shared__ float tile[32][33];
  int tx = threadIdx.x, ty = threadIdx.y;
  int c0 = blockIdx.x * 32, r0 = blockIdx.y * 32;
#pragma unroll
  for (int j = ty; j < 32; j += 8)
    tile[j][tx] = in[(size_t)(r0 + j) * C + c0 + tx];
  __syncthreads();
#pragma unroll
  for (int j = ty; j < 32; j += 8)
    out[(size_t)(c0 + j) * R + r0 + tx] = f2bf(tile[tx][j]);
}

// ---------------- bf16 GEMM, B^T layout (m97 structure + T1 swizzle) --------
template<int EPI>
__global__ __launch_bounds__(256) void gemm_bt(
    const unsigned short* __restrict__ A,
    const unsigned short* __restrict__ Bt,
    const float* __restrict__ bias,
    unsigned short* __restrict__ qp,
    unsigned short* __restrict__ kp,
    unsigned short* __restrict__ vp,
    float* __restrict__ outp,
    int M, int N, int K)
{
  __shared__ unsigned short As[128 * 64];
  __shared__ unsigned short Bs[128 * 64];
  const int tid = threadIdx.x;
  const int w = tid >> 6, lane = tid & 63;
  const int lr = lane & 15, lg = lane >> 4;
  // T1: bijective XCD swizzle (nwg % 8 == 0 for both launches)
  const int gx = gridDim.x;
  const int lin = (int)(blockIdx.y * gx + blockIdx.x);
  const int cpx = (int)(gx * gridDim.y) >> 3;
  const int wg = (lin & 7) * cpx + (lin >> 3);
  const int m0 = (wg % gx) * 128, n0 = (wg / gx) * 128;
  const int wm = (w >> 1) * 64, wn = (w & 1) * 64;
  const int fbase = w * 4;
  f32x4 acc[4][4] = {};

  for (int kt = 0; kt < K; kt += 64) {
    __syncthreads();
#pragma unroll
    for (int i = 0; i < 4; i++) {
      int f = (fbase + i) * 64 + lane;
      int row = f >> 3, col = (f & 7) * 8;
      gload_lds16(A  + (size_t)(m0 + row) * K + kt + col, &As[(fbase + i) * 512]);
      gload_lds16(Bt + (size_t)(n0 + row) * K + kt + col, &Bs[(fbase + i) * 512]);
    }
    __syncthreads();
#pragma unroll
    for (int kk = 0; kk < 2; kk++) {
      bf16x8 af[4], bv[4];
#pragma unroll
      for (int mi = 0; mi < 4; mi++)
        af[mi] = *(const bf16x8*)&As[(wm + mi * 16 + lr) * 64 + kk * 32 + lg * 8];
#pragma unroll
      for (int ni = 0; ni < 4; ni++)
        bv[ni] = *(const bf16x8*)&Bs[(wn + ni * 16 + lr) * 64 + kk * 32 + lg * 8];
#pragma unroll
      for (int mi = 0; mi < 4; mi++)
#pragma unroll
        for (int ni = 0; ni < 4; ni++)
          acc[mi][ni] = __builtin_amdgcn_mfma_f32_16x16x32_bf16(af[mi], bv[ni], acc[mi][ni], 0, 0, 0);
    }
  }

#pragma unroll
  for (int mi = 0; mi < 4; mi++)
#pragma unroll
    for (int ni = 0; ni < 4; ni++) {
      const int rowb = m0 + wm + mi * 16 + lg * 4;
      const int colb = n0 + wn + ni * 16 + lr;
      const float bv_ = bias[colb];
      if (EPI == 0) {
        int s = colb >> 10, hh = (colb & 1023) >> 6, d = colb & 63;
        int b = rowb >> 11, t = rowb & 2047;
        if (s == 2) {
          ushort4 o4;
          o4.x = f2bf(acc[mi][ni][0] + bv_);
          o4.y = f2bf(acc[mi][ni][1] + bv_);
          o4.z = f2bf(acc[mi][ni][2] + bv_);
          o4.w = f2bf(acc[mi][ni][3] + bv_);
          *(ushort4*)&vp[((size_t)(b * NHEAD + hh) * HDIM + d) * SEQ + t] = o4;
        } else {
          // Q gets 1/sqrt(D)*log2(e) pre-folded (attention works in base-2)
          unsigned short* dst = (s == 0) ? qp : kp;
          const float scl = (s == 0) ? 0.18033688f : 1.0f;
#pragma unroll
          for (int r = 0; r < 4; r++)
            dst[((size_t)(b * NHEAD + hh) * SEQ + t + r) * HDIM + d] =
                f2bf((acc[mi][ni][r] + bv_) * scl);
        }
      } else {
#pragma unroll
        for (int r = 0; r < 4; r++)
          outp[(size_t)(rowb + r) * N + colb] = acc[mi][ni][r] + bv_;
      }
    }
}

// --------- softmax for one 16q x 64k fragment (swapped S^T layout) ---------
__device__ __forceinline__ void softmax_frag(
    f32x4 (&s)[4], float& m, f32x4& su, f32x4 (&o)[4],
    unsigned short* psrow, int qrow, int kbase, bool needmask,
    int lg, int lr, int pswz)
{
  const float NEG = -1e30f;
  float pm = NEG;
  if (needmask) {
#pragma unroll
    for (int n = 0; n < 4; n++)
#pragma unroll
      for (int r = 0; r < 4; r++) {
        float sv = s[n][r];
        if (kbase + n * 16 + lg * 4 + r > qrow) sv = NEG;
        s[n][r] = sv;
        pm = fmaxf(pm, sv);
      }
  } else {
#pragma unroll
    for (int n = 0; n < 4; n++)
#pragma unroll
      for (int r = 0; r < 4; r++) pm = fmaxf(pm, s[n][r]);
  }
  // defer-max (T13): common path skips the cross-lane reduce entirely
  if (__any(pm > m + 8.f)) {
    pm = fmaxf(pm, __shfl_xor(pm, 16, 64));
    pm = fmaxf(pm, __shfl_xor(pm, 32, 64));
    float mn = fmaxf(m, pm);
    float fac = exp2f(m - mn);
    m = mn;
    float fr[4];
#pragma unroll
    for (int r = 0; r < 4; r++) fr[r] = __shfl(fac, lg * 4 + r, 64);
#pragma unroll
    for (int r = 0; r < 4; r++) su[r] *= fr[r];
#pragma unroll
    for (int n = 0; n < 4; n++)
#pragma unroll
      for (int r = 0; r < 4; r++) o[n][r] *= fr[r];
  }
#pragma unroll
  for (int n = 0; n < 4; n++) {
    float p0 = exp2f(s[n][0] - m);
    float p1 = exp2f(s[n][1] - m);
    float p2 = exp2f(s[n][2] - m);
    float p3 = exp2f(s[n][3] - m);
    uint2 pk;
    pk.x = pack_bf2(p0, p1);
    pk.y = pack_bf2(p2, p3);
    int E = (lr * 64 + n * 16 + lg * 4) ^ pswz;
    *(uint2*)&psrow[E] = pk;
  }
}

// ---------------- causal flash attention, QBLK=128 ----------------
// Q,K: [BH][T][D] bf16 (Q pre-scaled).  Vt: [BH][D][T] bf16.  Y: [B*T][C].
// Grid (8, 64): block bx handles qb = 15-bx then qb = bx (34 k-tiles each).
__global__ __launch_bounds__(256) void attn_k(
    const unsigned short* __restrict__ Q,
    const unsigned short* __restrict__ K,
    const unsigned short* __restrict__ Vt,
    unsigned short* __restrict__ Y)
{
  __shared__ unsigned short Ks[2][64 * 64];
  __shared__ unsigned short Vs[2][64 * 64];
  __shared__ unsigned short Ps[4][32 * 64];

  const int tid = threadIdx.x;
  const int w = tid >> 6, lane = tid & 63;
  const int lr = lane & 15, lg = lane >> 4;
  const int bh = blockIdx.y;
  const int b = bh >> 4, h = bh & 15;
  const size_t base = (size_t)bh * SEQ * HDIM;
  const float NEG = -1e30f;
  const int pswz = (lr & 7) << 3;

  bf16x8 ones;
#pragma unroll
  for (int e = 0; e < 8; e++) ones[e] = (short)0x3F80;  // bf16 1.0

  // staging geometry (linear LDS dest, pre-swizzled global source)
  const int f0 = w * 128 + lane, f1 = f0 + 64;
  const int r0_ = f0 >> 3, c0_ = ((f0 & 7) ^ (r0_ & 7)) * 8;
  const int r1_ = f1 >> 3, c1_ = ((f1 & 7) ^ (r1_ & 7)) * 8;

  for (int seg = 0; seg < 2; seg++) {
    const int qb = seg ? (int)blockIdx.x : (15 - (int)blockIdx.x);
    const int qw0 = qb * 128 + w * 32;
    const int nk = 2 * qb + 2;

    bf16x8 aq[2][2];
#pragma unroll
    for (int f = 0; f < 2; f++)
#pragma unroll
      for (int kk = 0; kk < 2; kk++)
        aq[f][kk] = *(const bf16x8*)
            &Q[base + (size_t)(qw0 + f * 16 + lr) * HDIM + kk * 32 + lg * 8];

    f32x4 o0[4] = {}, o1[4] = {};
    f32x4 su0 = {}, su1 = {};
    float m0 = NEG, m1 = NEG;

    // stage tile 0 into buf 0
    {
      const unsigned short* kxp = K + base;
      const unsigned short* vxp = Vt + base;
      gload_lds16(kxp + r0_ * HDIM + c0_, &Ks[0][f0 * 8]);
      gload_lds16(kxp + r1_ * HDIM + c1_, &Ks[0][f1 * 8]);
      gload_lds16(vxp + (size_t)r0_ * SEQ + c0_, &Vs[0][f0 * 8]);
      gload_lds16(vxp + (size_t)r1_ * SEQ + c1_, &Vs[0][f1 * 8]);
    }
    __syncthreads();

    int cur = 0;
    for (int kb = 0; kb < nk; kb++) {
      if (kb + 1 < nk) {
        const unsigned short* kxp = K + base + (size_t)(kb + 1) * 64 * HDIM;
        const unsigned short* vxp = Vt + base + (kb + 1) * 64;
        gload_lds16(kxp + r0_ * HDIM + c0_, &Ks[cur ^ 1][f0 * 8]);
        gload_lds16(kxp + r1_ * HDIM + c1_, &Ks[cur ^ 1][f1 * 8]);
        gload_lds16(vxp + (size_t)r0_ * SEQ + c0_, &Vs[cur ^ 1][f0 * 8]);
        gload_lds16(vxp + (size_t)r1_ * SEQ + c1_, &Vs[cur ^ 1][f1 * 8]);
      }

      // fully-masked (wave,tile) pairs skip compute (barrier still hit)
      const bool active = (kb * 64 <= qw0 + 31);
      if (active) {
        // ---- S^T = K Q^T for both q-frags; bk shared ----
        f32x4 s0[4] = {}, s1[4] = {};
        __builtin_amdgcn_s_setprio(1);
#pragma unroll
        for (int kk = 0; kk < 2; kk++) {
          bf16x8 bk[4];
#pragma unroll
          for (int n = 0; n < 4; n++) {
            int E = (n * 16 + lr) * 64 + kk * 32 + lg * 8;
            bk[n] = *(const bf16x8*)&Ks[cur][E ^ pswz];
          }
#pragma unroll
          for (int n = 0; n < 4; n++) {
            s0[n] = __builtin_amdgcn_mfma_f32_16x16x32_bf16(bk[n], aq[0][kk], s0[n], 0, 0, 0);
            s1[n] = __builtin_amdgcn_mfma_f32_16x16x32_bf16(bk[n], aq[1][kk], s1[n], 0, 0, 0);
          }
        }
        __builtin_amdgcn_s_setprio(0);

        const int kbase = kb * 64;
        softmax_frag(s0, m0, su0, o0, &Ps[w][0],
                     qw0 + lr, kbase, kbase + 63 > qw0, lg, lr, pswz);
        softmax_frag(s1, m1, su1, o1, &Ps[w][16 * 64],
                     qw0 + 16 + lr, kbase, kbase + 63 > qw0 + 16, lg, lr, pswz);

        // ---- O += P V ; row-sums via ones-column MFMA ----
        __builtin_amdgcn_s_setprio(1);
#pragma unroll
        for (int kc = 0; kc < 2; kc++) {
          bf16x8 ap0 = *(const bf16x8*)&Ps[w][(lr * 64 + kc * 32 + lg * 8) ^ pswz];
          bf16x8 ap1 = *(const bf16x8*)&Ps[w][((16 + lr) * 64 + kc * 32 + lg * 8) ^ pswz];
          su0 = __builtin_amdgcn_mfma_f32_16x16x32_bf16(ap0, ones, su0, 0, 0, 0);
          su1 = __builtin_amdgcn_mfma_f32_16x16x32_bf16(ap1, ones, su1, 0, 0, 0);
#pragma unroll
          for (int n = 0; n < 4; n++) {
            int E = (n * 16 + lr) * 64 + kc * 32 + lg * 8;
            bf16x8 bv = *(const bf16x8*)&Vs[cur][E ^ pswz];
            o0[n] = __builtin_amdgcn_mfma_f32_16x16x32_bf16(ap0, bv, o0[n], 0, 0, 0);
            o1[n] = __builtin_amdgcn_mfma_f32_16x16x32_bf16(ap1, bv, o1[n], 0, 0, 0);
          }
        }
        __builtin_amdgcn_s_setprio(0);
      }

      __syncthreads();
      cur ^= 1;
    }

    // ---- epilogue: normalize (su already in O-layout) and write Y ----
    float inv0[4], inv1[4];
#pragma unroll
    for (int r = 0; r < 4; r++) { inv0[r] = 1.f / su0[r]; inv1[r] = 1.f / su1[r]; }
#pragma unroll
    for (int n = 0; n < 4; n++)
#pragma unroll
      for (int r = 0; r < 4; r++) {
        int col = h * HDIM + n * 16 + lr;
        int t0 = qw0 + lg * 4 + r;
        Y[((size_t)(b * SEQ + t0)) * EMBED + col] = f2bf(o0[n][r] * inv0[r]);
        int t1 = qw0 + 16 + lg * 4 + r;
        Y[((size_t)(b * SEQ + t1)) * EMBED + col] = f2bf(o1[n][r] * inv1[r]);
      }
  }
}

// ---------------- host launch ----------------
extern "C" void kernel_launch(void* const* d_in, const int* in_sizes, int n_in,
                              void* d_out, int out_size, void* d_ws, size_t ws_size,
                              hipStream_t stream) {
  const float* x     = (const float*)d_in[0];
  const float* w_qkv = (const float*)d_in[1];
  const float* b_qkv = (const float*)d_in[2];
  const float* w_out = (const float*)d_in[3];
  const float* b_out = (const float*)d_in[4];
  float* outp = (float*)d_out;

  char* ws = (char*)d_ws;
  unsigned short* xb    = (unsigned short*)ws; ws += (size_t)BT * EMBED * 2;
  unsigned short* wqkvT = (unsigned short*)ws; ws += (size_t)NQKV * EMBED * 2;
  unsigned short* woutT = (unsigned short*)ws; ws += (size_t)EMBED * EMBED * 2;
  unsigned short* Qb    = (unsigned short*)ws; ws += (size_t)BATCH * NHEAD * SEQ * HDIM * 2;
  unsigned short* Kb    = (unsigned short*)ws; ws += (size_t)BATCH * NHEAD * SEQ * HDIM * 2;
  unsigned short* Vb    = (unsigned short*)ws; ws += (size_t)BATCH * NHEAD * SEQ * HDIM * 2;
  unsigned short* Yb    = (unsigned short*)ws; ws += (size_t)BT * EMBED * 2;

  cvt_f32_bf16_k<<<(BT * EMBED) / 1024, 256, 0, stream>>>(x, xb, BT * EMBED);
  transpose_cvt_k<<<dim3(NQKV / 32, EMBED / 32), dim3(32, 8), 0, stream>>>(w_qkv, wqkvT, EMBED, NQKV);
  transpose_cvt_k<<<dim3(EMBED / 32, EMBED / 32), dim3(32, 8), 0, stream>>>(w_out, woutT, EMBED, EMBED);

  gemm_bt<0><<<dim3(BT / 128, NQKV / 128), 256, 0, stream>>>(
      xb, wqkvT, b_qkv, Qb, Kb, Vb, nullptr, BT, NQKV, EMBED);

  attn_k<<<dim3(SEQ / 256, BATCH * NHEAD), 256, 0, stream>>>(Qb, Kb, Vb, Yb);

  gemm_bt<1><<<dim3(BT / 128, EMBED / 128), 256, 0, stream>>>(
      Yb, woutT, b_out, nullptr, nullptr, nullptr, outp, BT, EMBED, EMBED);
}